// Round 3
// baseline (758.660 us; speedup 1.0000x reference)
//
#include <hip/hip_runtime.h>
#include <math.h>

typedef unsigned short u16;
typedef unsigned int u32;
typedef __attribute__((ext_vector_type(8))) short short8;
typedef __attribute__((ext_vector_type(4))) float f32x4;

__device__ __forceinline__ float b2f(u16 u) {
    return __uint_as_float(((u32)u) << 16);
}
__device__ __forceinline__ u16 f2b(float f) {
    u32 x = __float_as_uint(f);
    return (u16)((x + 0x7fffu + ((x >> 16) & 1u)) >> 16);   // RNE
}
// load/store an element of an EXTERNAL tensor whose dtype is decided by flag
__device__ __forceinline__ float ldext(const void* p, size_t i, int isbf) {
    return isbf ? b2f(((const u16*)p)[i]) : ((const float*)p)[i];
}
__device__ __forceinline__ void stext(void* p, size_t i, int isbf, float v) {
    if (isbf) ((u16*)p)[i] = f2b(v);
    else ((float*)p)[i] = v;
}

// ---------- dtype detector: writes 1 if h looks like bf16, 0 if f32 ----------
__global__ void detect_k(const void* __restrict__ h, int* __restrict__ flag) {
    __shared__ int cnt;
    if (threadIdx.x == 0) cnt = 0;
    __syncthreads();
    const u16* p = (const u16*)h;
    int local = 0;
    for (int i = threadIdx.x; i < 4096; i += 256) {
        int e = (p[i] >> 7) & 0xFF;                 // bf16 exponent field
        if (e != 0 && (e < 110 || e > 133)) local++; // |x| outside [~1e-5, ~64]
    }
    atomicAdd(&cnt, local);
    __syncthreads();
    if (threadIdx.x == 0) *flag = (cnt < 256) ? 1 : 0;
}

// ---------- transpose ext weight -> bf16 [C][R] ----------
__global__ void transpose_k(const void* __restrict__ src, u16* __restrict__ dst,
                            int R, int C, const int* __restrict__ flag) {
    int isbf = *flag;
    int idx = blockIdx.x * 256 + threadIdx.x;
    if (idx >= R * C) return;
    int r = idx / C, c = idx - r * C;
    dst[c * R + r] = f2b(ldext(src, idx, isbf));
}

// ---------- arsinh norm: y = w[c]*asinh(x) + b[c]; ext in -> bf16 out ----------
__global__ void norm_k(const void* __restrict__ xb, size_t xoff,
                       const void* __restrict__ w, const void* __restrict__ b,
                       u16* __restrict__ y, const int* __restrict__ flag) {
    int isbf = *flag;
    size_t base = ((size_t)blockIdx.x * 256 + threadIdx.x) * 4;
    int c0 = (int)(base & 255);
    float v[4];
    if (isbf) {
        uint2 raw = *reinterpret_cast<const uint2*>((const u16*)xb + xoff + base);
        const u16* px = reinterpret_cast<const u16*>(&raw);
#pragma unroll
        for (int j = 0; j < 4; ++j) v[j] = b2f(px[j]);
    } else {
        float4 r = *reinterpret_cast<const float4*>((const float*)xb + xoff + base);
        v[0] = r.x; v[1] = r.y; v[2] = r.z; v[3] = r.w;
    }
    u16 o[4];
#pragma unroll
    for (int j = 0; j < 4; ++j)
        o[j] = f2b(ldext(w, c0 + j, isbf) * asinhf(v[j]) + ldext(b, c0 + j, isbf));
    *reinterpret_cast<uint2*>(y + base) = *reinterpret_cast<uint2*>(o);
}

// ---------- GEMM: C[M][N] = A[M][K] @ BT[N][K]^T + bias(ext), bf16 MFMA ----------
// EPI 0: store bf16 to outi
// EPI 1: exact GELU, store bf16 to outi
// EPI 2: + ext residual (resb,resoff), store ext (outb,outoff)
template <int EPI>
__global__ __launch_bounds__(256) void gemm_bt(
    const u16* __restrict__ A, const u16* __restrict__ BT, const void* __restrict__ bias,
    const void* __restrict__ resb, size_t resoff, void* __restrict__ outb, size_t outoff,
    u16* __restrict__ outi, int N, int K, const int* __restrict__ flag) {
    __shared__ __align__(16) u16 lA[128 * 32];
    __shared__ __align__(16) u16 lB[128 * 32];
    const int isbf = *flag;
    const int tid = threadIdx.x;
    const int lane = tid & 63;
    const int wave = tid >> 6;
    const int waveM = wave >> 1, waveN = wave & 1;
    const int m0 = blockIdx.y * 128;
    const int n0 = blockIdx.x * 128;

    f32x4 acc[4][4];
#pragma unroll
    for (int mi = 0; mi < 4; ++mi)
#pragma unroll
        for (int ni = 0; ni < 4; ++ni)
#pragma unroll
            for (int r = 0; r < 4; ++r) acc[mi][ni][r] = 0.f;

    const int lrow = lane & 15;
    const int ko = (lane >> 4) * 8;

    for (int k0 = 0; k0 < K; k0 += 32) {
        __syncthreads();
#pragma unroll
        for (int pp = 0; pp < 2; ++pp) {
            int e0 = (pp * 256 + tid) * 8;
            int row = e0 >> 5, col = e0 & 31;
            *reinterpret_cast<uint4*>(&lA[e0]) =
                *reinterpret_cast<const uint4*>(&A[(size_t)(m0 + row) * K + k0 + col]);
            *reinterpret_cast<uint4*>(&lB[e0]) =
                *reinterpret_cast<const uint4*>(&BT[(size_t)(n0 + row) * K + k0 + col]);
        }
        __syncthreads();
        short8 af[4], bfr[4];
#pragma unroll
        for (int mi = 0; mi < 4; ++mi)
            af[mi] = *reinterpret_cast<const short8*>(&lA[(waveM * 64 + mi * 16 + lrow) * 32 + ko]);
#pragma unroll
        for (int ni = 0; ni < 4; ++ni)
            bfr[ni] = *reinterpret_cast<const short8*>(&lB[(waveN * 64 + ni * 16 + lrow) * 32 + ko]);
#pragma unroll
        for (int mi = 0; mi < 4; ++mi)
#pragma unroll
            for (int ni = 0; ni < 4; ++ni)
                acc[mi][ni] = __builtin_amdgcn_mfma_f32_16x16x32_bf16(af[mi], bfr[ni], acc[mi][ni], 0, 0, 0);
    }

    const int rquad = (lane >> 4) * 4;
    const int ccol = lane & 15;
#pragma unroll
    for (int mi = 0; mi < 4; ++mi)
#pragma unroll
        for (int ni = 0; ni < 4; ++ni) {
            int colg = n0 + waveN * 64 + ni * 16 + ccol;
            float bb = ldext(bias, colg, isbf);
#pragma unroll
            for (int r = 0; r < 4; ++r) {
                int rowg = m0 + waveM * 64 + mi * 16 + rquad + r;
                size_t idx = (size_t)rowg * N + colg;
                float v = acc[mi][ni][r] + bb;
                if (EPI == 0) {
                    outi[idx] = f2b(v);
                } else if (EPI == 1) {
                    v = 0.5f * v * (1.f + erff(v * 0.70710678118654752f));
                    outi[idx] = f2b(v);
                } else {
                    v += ldext(resb, resoff + idx, isbf);
                    stext(outb, outoff + idx, isbf, v);
                }
            }
        }
}

// ---------- neighborhood attention (3x3, clamped), per chunk of whole images ----------
// qkv: [CHUNK][768] bf16 (q|k|v, each 256 = 8 heads x 32). out: [CHUNK][256] bf16.
__global__ __launch_bounds__(256) void attn_k(const u16* __restrict__ qkv, u16* __restrict__ out) {
    const int p = blockIdx.x;   // token within chunk
    const int c = threadIdx.x;  // channel = head*32 + d
    const int b = p >> 12;      // image within chunk
    const int ij = p & 4095;
    const int i = ij >> 6, j = ij & 63;
    int r0 = i - 1; r0 = r0 < 0 ? 0 : (r0 > 61 ? 61 : r0);
    int c0 = j - 1; c0 = c0 < 0 ? 0 : (c0 > 61 ? 61 : c0);

    const float qscale = 0.17677669529663687f;  // 32^-0.5
    float qv = b2f(qkv[(size_t)p * 768 + c]) * qscale;

    int nbp[9];
    float sc[9];
#pragma unroll
    for (int dr = 0; dr < 3; ++dr)
#pragma unroll
        for (int dc = 0; dc < 3; ++dc) {
            int nb = dr * 3 + dc;
            int np_ = b * 4096 + (r0 + dr) * 64 + (c0 + dc);
            nbp[nb] = np_;
            float prod = qv * b2f(qkv[(size_t)np_ * 768 + 256 + c]);
#pragma unroll
            for (int m = 16; m > 0; m >>= 1) prod += __shfl_xor(prod, m, 32);
            sc[nb] = prod;
        }
    float mx = sc[0];
#pragma unroll
    for (int nb = 1; nb < 9; ++nb) mx = fmaxf(mx, sc[nb]);
    float s = 0.f;
#pragma unroll
    for (int nb = 0; nb < 9; ++nb) { sc[nb] = __expf(sc[nb] - mx); s += sc[nb]; }
    float inv = 1.f / s;
    float acc = 0.f;
#pragma unroll
    for (int nb = 0; nb < 9; ++nb)
        acc += sc[nb] * inv * b2f(qkv[(size_t)nbp[nb] * 768 + 512 + c]);
    out[(size_t)p * 256 + c] = f2b(acc);
}

extern "C" void kernel_launch(void* const* d_in, const int* in_sizes, int n_in,
                              void* d_out, int out_size, void* d_ws, size_t ws_size,
                              hipStream_t stream) {
    const void* h      = d_in[0];
    const void* qkv_w  = d_in[1];
    const void* qkv_b  = d_in[2];
    const void* proj_w = d_in[3];
    const void* proj_b = d_in[4];
    const void* n1_w   = d_in[5];
    const void* n1_b   = d_in[6];
    const void* n2_w   = d_in[7];
    const void* n2_b   = d_in[8];
    const void* w1     = d_in[9];
    const void* b1     = d_in[10];
    const void* w2     = d_in[11];
    const void* b2     = d_in[12];

    // workspace layout: weights (bf16-transposed) + flag + chunk buffers
    char* ws = (char*)d_ws;
    u16* WqkvT  = (u16*)(ws + 0);          // [768][256]  393,216 B
    u16* WprojT = (u16*)(ws + 393216);     // [256][256]  131,072 B
    u16* W1T    = (u16*)(ws + 524288);     // [512][256]  262,144 B
    u16* W2T    = (u16*)(ws + 786432);     // [256][512]  262,144 B
    int* Flag   = (int*)(ws + 1048576);    // 4 B (+pad to 1024)
    char* bufs  = ws + 1049600;

    // runtime chunk size: CHUNK tokens (whole 4096-token images), footprint = CHUNK*2048 B
    size_t avail = ws_size > 1049600 ? ws_size - 1049600 : 0;
    int CHUNK = 4096;
    if (avail >= (size_t)16384 * 2048) CHUNK = 16384;
    else if (avail >= (size_t)8192 * 2048) CHUNK = 8192;
    u16* H1 = (u16*)bufs;                         // [CHUNK][256] bf16: h1 / attnout / h2
    u16* S  = (u16*)(bufs + (size_t)CHUNK * 512); // [CHUNK][768] bf16: qkv / t
    const int NCH = 65536 / CHUNK;

    detect_k<<<1, 256, 0, stream>>>(h, Flag);
    transpose_k<<<768, 256, 0, stream>>>(qkv_w, WqkvT, 256, 768, Flag);
    transpose_k<<<256, 256, 0, stream>>>(proj_w, WprojT, 256, 256, Flag);
    transpose_k<<<512, 256, 0, stream>>>(w1, W1T, 256, 512, Flag);
    transpose_k<<<512, 256, 0, stream>>>(w2, W2T, 512, 256, Flag);

    // phase 1: hnew = h + proj(attn(qkv(norm1(h))))  -> d_out (ext dtype), per chunk
    for (int c = 0; c < NCH; ++c) {
        size_t off = (size_t)c * CHUNK * 256;
        norm_k<<<CHUNK / 4, 256, 0, stream>>>(h, off, n1_w, n1_b, H1, Flag);
        { dim3 g(6, CHUNK / 128);
          gemm_bt<0><<<g, 256, 0, stream>>>(H1, WqkvT, qkv_b, nullptr, 0, nullptr, 0, S, 768, 256, Flag); }
        attn_k<<<CHUNK, 256, 0, stream>>>(S, H1);
        { dim3 g(2, CHUNK / 128);
          gemm_bt<2><<<g, 256, 0, stream>>>(H1, WprojT, proj_b, h, off, d_out, off, nullptr, 256, 256, Flag); }
    }

    // phase 2: out = hnew + mlp2(gelu(mlp1(norm2(hnew)))), d_out updated in place
    for (int c = 0; c < NCH; ++c) {
        size_t off = (size_t)c * CHUNK * 256;
        norm_k<<<CHUNK / 4, 256, 0, stream>>>(d_out, off, n2_w, n2_b, H1, Flag);
        { dim3 g(4, CHUNK / 128);
          gemm_bt<1><<<g, 256, 0, stream>>>(H1, W1T, b1, nullptr, 0, nullptr, 0, S, 512, 256, Flag); }
        { dim3 g(2, CHUNK / 128);
          gemm_bt<2><<<g, 256, 0, stream>>>(S, W2T, b2, d_out, off, d_out, off, nullptr, 256, 512, Flag); }
    }
}

// Round 4
// 597.508 us; speedup vs baseline: 1.2697x; 1.2697x over previous
//
#include <hip/hip_runtime.h>
#include <math.h>

typedef unsigned short u16;
typedef unsigned int u32;
typedef __attribute__((ext_vector_type(8))) short short8;
typedef __attribute__((ext_vector_type(4))) float f32x4;

__device__ __forceinline__ float b2f(u16 u) {
    return __uint_as_float(((u32)u) << 16);
}
__device__ __forceinline__ u16 f2b(float f) {
    u32 x = __float_as_uint(f);
    return (u16)((x + 0x7fffu + ((x >> 16) & 1u)) >> 16);   // RNE
}
__device__ __forceinline__ float ldext(const void* p, size_t i, int isbf) {
    return isbf ? b2f(((const u16*)p)[i]) : ((const float*)p)[i];
}
__device__ __forceinline__ void stext(void* p, size_t i, int isbf, float v) {
    if (isbf) ((u16*)p)[i] = f2b(v);
    else ((float*)p)[i] = v;
}
// async global->LDS, 16B per lane; lds base must be wave-uniform (HW adds lane*16)
__device__ __forceinline__ void gl2lds16(const u16* g, u16* l) {
    __builtin_amdgcn_global_load_lds(
        (const __attribute__((address_space(1))) u32*)(const void*)g,
        (__attribute__((address_space(3))) u32*)(void*)l, 16, 0, 0);
}

// ---------- dtype detector: 1 if h is bf16, 0 if f32 ----------
__global__ void detect_k(const void* __restrict__ h, int* __restrict__ flag) {
    __shared__ int cnt;
    if (threadIdx.x == 0) cnt = 0;
    __syncthreads();
    const u16* p = (const u16*)h;
    int local = 0;
    for (int i = threadIdx.x; i < 4096; i += 256) {
        int e = (p[i] >> 7) & 0xFF;
        if (e != 0 && (e < 110 || e > 133)) local++;
    }
    atomicAdd(&cnt, local);
    __syncthreads();
    if (threadIdx.x == 0) *flag = (cnt < 256) ? 1 : 0;
}

// ---------- transpose ext weight -> bf16 [C][R] ----------
__global__ void transpose_k(const void* __restrict__ src, u16* __restrict__ dst,
                            int R, int C, const int* __restrict__ flag) {
    int isbf = *flag;
    int idx = blockIdx.x * 256 + threadIdx.x;
    if (idx >= R * C) return;
    int r = idx / C, c = idx - r * C;
    dst[c * R + r] = f2b(ldext(src, idx, isbf));
}

// ---------- arsinh norm: y = w[c]*asinh(x)+b[c]; in: ext or forced-bf16; out bf16 ----------
__global__ void norm_k(const void* __restrict__ xb, size_t xoff,
                       const void* __restrict__ w, const void* __restrict__ b,
                       u16* __restrict__ y, const int* __restrict__ flag, int force_bf) {
    int isbf = *flag;
    int xisbf = force_bf ? 1 : isbf;
    size_t base = ((size_t)blockIdx.x * 256 + threadIdx.x) * 4;
    int c0 = (int)(base & 255);
    float v[4];
    if (xisbf) {
        uint2 raw = *reinterpret_cast<const uint2*>((const u16*)xb + xoff + base);
        const u16* px = reinterpret_cast<const u16*>(&raw);
#pragma unroll
        for (int j = 0; j < 4; ++j) v[j] = b2f(px[j]);
    } else {
        float4 r = *reinterpret_cast<const float4*>((const float*)xb + xoff + base);
        v[0] = r.x; v[1] = r.y; v[2] = r.z; v[3] = r.w;
    }
    u16 o[4];
#pragma unroll
    for (int j = 0; j < 4; ++j)
        o[j] = f2b(ldext(w, c0 + j, isbf) * asinhf(v[j]) + ldext(b, c0 + j, isbf));
    *reinterpret_cast<uint2*>(y + base) = *reinterpret_cast<uint2*>(o);
}

// ---------- GEMM: C[M][N] = A[M][K] @ BT[N][K]^T + bias(ext), bf16 MFMA ----------
// EPI 0: store bf16            1: GELU, store bf16
// EPI 2: +res ext, store ext   3: +res ext, store bf16   4: +res bf16, store ext
template <int EPI>
__global__ __launch_bounds__(256) void gemm_bt(
    const u16* __restrict__ A, const u16* __restrict__ BT, const void* __restrict__ bias,
    const void* __restrict__ resb, size_t resoff, void* __restrict__ outb, size_t outoff,
    int N, int K, const int* __restrict__ flag) {
    __shared__ __align__(16) u16 lA[128 * 32];
    __shared__ __align__(16) u16 lB[128 * 32];
    const int isbf = *flag;
    const int tid = threadIdx.x;
    const int lane = tid & 63;
    const int wave = tid >> 6;
    const int waveM = wave >> 1, waveN = wave & 1;
    const int m0 = blockIdx.y * 128;
    const int n0 = blockIdx.x * 128;

    f32x4 acc[4][4];
#pragma unroll
    for (int mi = 0; mi < 4; ++mi)
#pragma unroll
        for (int ni = 0; ni < 4; ++ni)
#pragma unroll
            for (int r = 0; r < 4; ++r) acc[mi][ni][r] = 0.f;

    const int lrow = lane & 15;
    const int ko = (lane >> 4) * 8;
    // staging geometry: slot s = wave*2+q; element e0 = (s*64+lane)*8; row=e0>>5 col=e0&31
    const int srow0 = (wave * 128 + lane) >> 2;       // q=0 row: e0>>5 with q folded below
    // (compute per-q inside loop for clarity; cheap SALU/VALU)

    for (int k0 = 0; k0 < K; k0 += 32) {
        __syncthreads();
#pragma unroll
        for (int q = 0; q < 2; ++q) {
            int s = wave * 2 + q;
            int e0 = (s * 64 + lane) * 8;
            int row = e0 >> 5, col = e0 & 31;
            gl2lds16(&A[(size_t)(m0 + row) * K + k0 + col], &lA[s * 512]);
            gl2lds16(&BT[(size_t)(n0 + row) * K + k0 + col], &lB[s * 512]);
        }
        __syncthreads();
        short8 af[4], bfr[4];
#pragma unroll
        for (int mi = 0; mi < 4; ++mi)
            af[mi] = *reinterpret_cast<const short8*>(&lA[(waveM * 64 + mi * 16 + lrow) * 32 + ko]);
#pragma unroll
        for (int ni = 0; ni < 4; ++ni)
            bfr[ni] = *reinterpret_cast<const short8*>(&lB[(waveN * 64 + ni * 16 + lrow) * 32 + ko]);
#pragma unroll
        for (int mi = 0; mi < 4; ++mi)
#pragma unroll
            for (int ni = 0; ni < 4; ++ni)
                acc[mi][ni] = __builtin_amdgcn_mfma_f32_16x16x32_bf16(af[mi], bfr[ni], acc[mi][ni], 0, 0, 0);
    }
    (void)srow0;

    const int rquad = (lane >> 4) * 4;
    const int ccol = lane & 15;
#pragma unroll
    for (int mi = 0; mi < 4; ++mi)
#pragma unroll
        for (int ni = 0; ni < 4; ++ni) {
            int colg = n0 + waveN * 64 + ni * 16 + ccol;
            float bb = ldext(bias, colg, isbf);
#pragma unroll
            for (int r = 0; r < 4; ++r) {
                int rowg = m0 + waveM * 64 + mi * 16 + rquad + r;
                size_t idx = (size_t)rowg * N + colg;
                float v = acc[mi][ni][r] + bb;
                if (EPI == 0) {
                    ((u16*)outb)[outoff + idx] = f2b(v);
                } else if (EPI == 1) {
                    v = 0.5f * v * (1.f + erff(v * 0.70710678118654752f));
                    ((u16*)outb)[outoff + idx] = f2b(v);
                } else if (EPI == 2) {
                    v += ldext(resb, resoff + idx, isbf);
                    stext(outb, outoff + idx, isbf, v);
                } else if (EPI == 3) {
                    v += ldext(resb, resoff + idx, isbf);
                    ((u16*)outb)[outoff + idx] = f2b(v);
                } else {
                    v += b2f(((const u16*)resb)[resoff + idx]);
                    stext(outb, outoff + idx, isbf, v);
                }
            }
        }
}

// ---------- neighborhood attention (3x3, clamped); works per whole-image token range ----------
__global__ __launch_bounds__(256) void attn_k(const u16* __restrict__ qkv, u16* __restrict__ out) {
    const int p = blockIdx.x;
    const int c = threadIdx.x;
    const int b = p >> 12;
    const int ij = p & 4095;
    const int i = ij >> 6, j = ij & 63;
    int r0 = i - 1; r0 = r0 < 0 ? 0 : (r0 > 61 ? 61 : r0);
    int c0 = j - 1; c0 = c0 < 0 ? 0 : (c0 > 61 ? 61 : c0);

    const float qscale = 0.17677669529663687f;  // 32^-0.5
    float qv = b2f(qkv[(size_t)p * 768 + c]) * qscale;

    int nbp[9];
    float sc[9];
#pragma unroll
    for (int dr = 0; dr < 3; ++dr)
#pragma unroll
        for (int dc = 0; dc < 3; ++dc) {
            int nb = dr * 3 + dc;
            int np_ = b * 4096 + (r0 + dr) * 64 + (c0 + dc);
            nbp[nb] = np_;
            float prod = qv * b2f(qkv[(size_t)np_ * 768 + 256 + c]);
#pragma unroll
            for (int m = 16; m > 0; m >>= 1) prod += __shfl_xor(prod, m, 32);
            sc[nb] = prod;
        }
    float mx = sc[0];
#pragma unroll
    for (int nb = 1; nb < 9; ++nb) mx = fmaxf(mx, sc[nb]);
    float s = 0.f;
#pragma unroll
    for (int nb = 0; nb < 9; ++nb) { sc[nb] = __expf(sc[nb] - mx); s += sc[nb]; }
    float inv = 1.f / s;
    float acc = 0.f;
#pragma unroll
    for (int nb = 0; nb < 9; ++nb)
        acc += sc[nb] * inv * b2f(qkv[(size_t)nbp[nb] * 768 + 512 + c]);
    out[(size_t)p * 256 + c] = f2b(acc);
}

extern "C" void kernel_launch(void* const* d_in, const int* in_sizes, int n_in,
                              void* d_out, int out_size, void* d_ws, size_t ws_size,
                              hipStream_t stream) {
    const void* h      = d_in[0];
    const void* qkv_w  = d_in[1];
    const void* qkv_b  = d_in[2];
    const void* proj_w = d_in[3];
    const void* proj_b = d_in[4];
    const void* n1_w   = d_in[5];
    const void* n1_b   = d_in[6];
    const void* n2_w   = d_in[7];
    const void* n2_b   = d_in[8];
    const void* w1     = d_in[9];
    const void* b1     = d_in[10];
    const void* w2     = d_in[11];
    const void* b2     = d_in[12];

    char* ws = (char*)d_ws;
    u16* WqkvT  = (u16*)(ws + 0);          // [768][256]
    u16* WprojT = (u16*)(ws + 393216);     // [256][256]
    u16* W1T    = (u16*)(ws + 524288);     // [512][256]
    u16* W2T    = (u16*)(ws + 786432);     // [256][512]
    int* Flag   = (int*)(ws + 1048576);
    char* bufs  = ws + 1049600;

    size_t avail = ws_size > 1049600 ? ws_size - 1049600 : 0;
    int CHUNK = 4096;
    if (avail >= (size_t)65536 * 2048) CHUNK = 65536;
    else if (avail >= (size_t)16384 * 2048) CHUNK = 16384;
    else if (avail >= (size_t)8192 * 2048) CHUNK = 8192;

    u16* H1 = (u16*)bufs;                          // [CHUNK][256] bf16
    u16* S  = (u16*)(bufs + (size_t)CHUNK * 512);  // [CHUNK][768] bf16

    detect_k<<<1, 256, 0, stream>>>(h, Flag);
    transpose_k<<<768, 256, 0, stream>>>(qkv_w, WqkvT, 256, 768, Flag);
    transpose_k<<<256, 256, 0, stream>>>(proj_w, WprojT, 256, 256, Flag);
    transpose_k<<<512, 256, 0, stream>>>(w1, W1T, 256, 512, Flag);
    transpose_k<<<512, 256, 0, stream>>>(w2, W2T, 512, 256, Flag);

    if (CHUNK == 65536) {
        // full-M flow: 6 more launches, hnew kept bf16 inside S region
        u16* HNS = S;                               // [65536][256] bf16 (qkv dead after attn)
        u16* T   = S + (size_t)65536 * 256;         // [65536][512] bf16
        norm_k<<<16384, 256, 0, stream>>>(h, 0, n1_w, n1_b, H1, Flag, 0);
        { dim3 g(6, 512); gemm_bt<0><<<g, 256, 0, stream>>>(H1, WqkvT, qkv_b, nullptr, 0, S, 0, 768, 256, Flag); }
        attn_k<<<65536, 256, 0, stream>>>(S, H1);
        { dim3 g(2, 512); gemm_bt<3><<<g, 256, 0, stream>>>(H1, WprojT, proj_b, h, 0, HNS, 0, 256, 256, Flag); }
        norm_k<<<16384, 256, 0, stream>>>(HNS, 0, n2_w, n2_b, H1, Flag, 1);
        { dim3 g(4, 512); gemm_bt<1><<<g, 256, 0, stream>>>(H1, W1T, b1, nullptr, 0, T, 0, 512, 256, Flag); }
        { dim3 g(2, 512); gemm_bt<4><<<g, 256, 0, stream>>>(T, W2T, b2, HNS, 0, d_out, 0, 256, 512, Flag); }
    } else {
        const int NCH = 65536 / CHUNK;
        for (int c = 0; c < NCH; ++c) {
            size_t off = (size_t)c * CHUNK * 256;
            norm_k<<<CHUNK / 4, 256, 0, stream>>>(h, off, n1_w, n1_b, H1, Flag, 0);
            { dim3 g(6, CHUNK / 128);
              gemm_bt<0><<<g, 256, 0, stream>>>(H1, WqkvT, qkv_b, nullptr, 0, S, 0, 768, 256, Flag); }
            attn_k<<<CHUNK, 256, 0, stream>>>(S, H1);
            { dim3 g(2, CHUNK / 128);
              gemm_bt<2><<<g, 256, 0, stream>>>(H1, WprojT, proj_b, h, off, d_out, off, 256, 256, Flag); }
        }
        for (int c = 0; c < NCH; ++c) {
            size_t off = (size_t)c * CHUNK * 256;
            norm_k<<<CHUNK / 4, 256, 0, stream>>>(d_out, off, n2_w, n2_b, H1, Flag, 0);
            { dim3 g(4, CHUNK / 128);
              gemm_bt<1><<<g, 256, 0, stream>>>(H1, W1T, b1, nullptr, 0, S, 0, 512, 256, Flag); }
            { dim3 g(2, CHUNK / 128);
              gemm_bt<2><<<g, 256, 0, stream>>>(S, W2T, b2, d_out, off, d_out, off, 256, 512, Flag); }
        }
    }
}

// Round 5
// 520.078 us; speedup vs baseline: 1.4587x; 1.1489x over previous
//
#include <hip/hip_runtime.h>
#include <math.h>

typedef unsigned short u16;
typedef unsigned int u32;
typedef __attribute__((ext_vector_type(8))) short short8;
typedef __attribute__((ext_vector_type(4))) float f32x4;

__device__ __forceinline__ float b2f(u16 u) {
    return __uint_as_float(((u32)u) << 16);
}
__device__ __forceinline__ u16 f2b(float f) {
    u32 x = __float_as_uint(f);
    return (u16)((x + 0x7fffu + ((x >> 16) & 1u)) >> 16);   // RNE
}
__device__ __forceinline__ float ldext(const void* p, size_t i, int isbf) {
    return isbf ? b2f(((const u16*)p)[i]) : ((const float*)p)[i];
}
__device__ __forceinline__ void stext(void* p, size_t i, int isbf, float v) {
    if (isbf) ((u16*)p)[i] = f2b(v);
    else ((float*)p)[i] = v;
}
// async global->LDS, 16B per lane; lds base must be wave-uniform (HW adds lane*16)
__device__ __forceinline__ void gl2lds16(const u16* g, u16* l) {
    __builtin_amdgcn_global_load_lds(
        (const __attribute__((address_space(1))) u32*)(const void*)g,
        (__attribute__((address_space(3))) u32*)(void*)l, 16, 0, 0);
}
// unpack 8 bf16 (uint4) -> 8 f32
__device__ __forceinline__ void unpack8(uint4 w, float* f) {
    const u32* pw = (const u32*)&w;
#pragma unroll
    for (int k = 0; k < 4; ++k) {
        f[2 * k]     = __uint_as_float(pw[k] << 16);
        f[2 * k + 1] = __uint_as_float(pw[k] & 0xffff0000u);
    }
}

// ---------- dtype detector: 1 if h is bf16, 0 if f32 ----------
__global__ void detect_k(const void* __restrict__ h, int* __restrict__ flag) {
    __shared__ int cnt;
    if (threadIdx.x == 0) cnt = 0;
    __syncthreads();
    const u16* p = (const u16*)h;
    int local = 0;
    for (int i = threadIdx.x; i < 4096; i += 256) {
        int e = (p[i] >> 7) & 0xFF;
        if (e != 0 && (e < 110 || e > 133)) local++;
    }
    atomicAdd(&cnt, local);
    __syncthreads();
    if (threadIdx.x == 0) *flag = (cnt < 256) ? 1 : 0;
}

// ---------- transpose ext weight -> bf16 [C][R] ----------
__global__ void transpose_k(const void* __restrict__ src, u16* __restrict__ dst,
                            int R, int C, const int* __restrict__ flag) {
    int isbf = *flag;
    int idx = blockIdx.x * 256 + threadIdx.x;
    if (idx >= R * C) return;
    int r = idx / C, c = idx - r * C;
    dst[c * R + r] = f2b(ldext(src, idx, isbf));
}

// ---------- arsinh norm: y = w[c]*asinh(x)+b[c]; in: ext or forced-bf16; out bf16 ----------
__global__ void norm_k(const void* __restrict__ xb, size_t xoff,
                       const void* __restrict__ w, const void* __restrict__ b,
                       u16* __restrict__ y, const int* __restrict__ flag, int force_bf) {
    int isbf = *flag;
    int xisbf = force_bf ? 1 : isbf;
    size_t base = ((size_t)blockIdx.x * 256 + threadIdx.x) * 4;
    int c0 = (int)(base & 255);
    float v[4];
    if (xisbf) {
        uint2 raw = *reinterpret_cast<const uint2*>((const u16*)xb + xoff + base);
        const u16* px = reinterpret_cast<const u16*>(&raw);
#pragma unroll
        for (int j = 0; j < 4; ++j) v[j] = b2f(px[j]);
    } else {
        float4 r = *reinterpret_cast<const float4*>((const float*)xb + xoff + base);
        v[0] = r.x; v[1] = r.y; v[2] = r.z; v[3] = r.w;
    }
    u16 o[4];
#pragma unroll
    for (int j = 0; j < 4; ++j)
        o[j] = f2b(ldext(w, c0 + j, isbf) * asinhf(v[j]) + ldext(b, c0 + j, isbf));
    *reinterpret_cast<uint2*>(y + base) = *reinterpret_cast<uint2*>(o);
}

// ---------- GEMM: C[M][N] = A[M][K] @ BT[N][K]^T + bias(ext), bf16 MFMA ----------
// EPI 0: store bf16            1: GELU, store bf16
// EPI 2: +res ext, store ext   3: +res ext, store bf16   4: +res bf16, store ext
template <int EPI>
__global__ __launch_bounds__(256) void gemm_bt(
    const u16* __restrict__ A, const u16* __restrict__ BT, const void* __restrict__ bias,
    const void* __restrict__ resb, size_t resoff, void* __restrict__ outb, size_t outoff,
    int N, int K, const int* __restrict__ flag) {
    __shared__ __align__(16) u16 lA[128 * 32];
    __shared__ __align__(16) u16 lB[128 * 32];
    const int isbf = *flag;
    const int tid = threadIdx.x;
    const int lane = tid & 63;
    const int wave = tid >> 6;
    const int waveM = wave >> 1, waveN = wave & 1;
    const int m0 = blockIdx.y * 128;
    const int n0 = blockIdx.x * 128;

    f32x4 acc[4][4];
#pragma unroll
    for (int mi = 0; mi < 4; ++mi)
#pragma unroll
        for (int ni = 0; ni < 4; ++ni)
#pragma unroll
            for (int r = 0; r < 4; ++r) acc[mi][ni][r] = 0.f;

    const int lrow = lane & 15;
    const int ko = (lane >> 4) * 8;

    for (int k0 = 0; k0 < K; k0 += 32) {
        __syncthreads();
#pragma unroll
        for (int q = 0; q < 2; ++q) {
            int s = wave * 2 + q;
            int e0 = (s * 64 + lane) * 8;
            int row = e0 >> 5, col = e0 & 31;
            gl2lds16(&A[(size_t)(m0 + row) * K + k0 + col], &lA[s * 512]);
            gl2lds16(&BT[(size_t)(n0 + row) * K + k0 + col], &lB[s * 512]);
        }
        __syncthreads();
        short8 af[4], bfr[4];
#pragma unroll
        for (int mi = 0; mi < 4; ++mi)
            af[mi] = *reinterpret_cast<const short8*>(&lA[(waveM * 64 + mi * 16 + lrow) * 32 + ko]);
#pragma unroll
        for (int ni = 0; ni < 4; ++ni)
            bfr[ni] = *reinterpret_cast<const short8*>(&lB[(waveN * 64 + ni * 16 + lrow) * 32 + ko]);
#pragma unroll
        for (int mi = 0; mi < 4; ++mi)
#pragma unroll
            for (int ni = 0; ni < 4; ++ni)
                acc[mi][ni] = __builtin_amdgcn_mfma_f32_16x16x32_bf16(af[mi], bfr[ni], acc[mi][ni], 0, 0, 0);
    }

    const int rquad = (lane >> 4) * 4;
    const int ccol = lane & 15;
#pragma unroll
    for (int mi = 0; mi < 4; ++mi)
#pragma unroll
        for (int ni = 0; ni < 4; ++ni) {
            int colg = n0 + waveN * 64 + ni * 16 + ccol;
            float bb = ldext(bias, colg, isbf);
#pragma unroll
            for (int r = 0; r < 4; ++r) {
                int rowg = m0 + waveM * 64 + mi * 16 + rquad + r;
                size_t idx = (size_t)rowg * N + colg;
                float v = acc[mi][ni][r] + bb;
                if (EPI == 0) {
                    ((u16*)outb)[outoff + idx] = f2b(v);
                } else if (EPI == 1) {
                    v = 0.5f * v * (1.f + erff(v * 0.70710678118654752f));
                    ((u16*)outb)[outoff + idx] = f2b(v);
                } else if (EPI == 2) {
                    v += ldext(resb, resoff + idx, isbf);
                    stext(outb, outoff + idx, isbf, v);
                } else if (EPI == 3) {
                    v += ldext(resb, resoff + idx, isbf);
                    ((u16*)outb)[outoff + idx] = f2b(v);
                } else {
                    v += b2f(((const u16*)resb)[resoff + idx]);
                    stext(outb, outoff + idx, isbf, v);
                }
            }
        }
}

// ---------- neighborhood attention v2: thread = (pixel, head), all in registers ----------
// qkv: [P][768] bf16 (q|k|v, each 256 = 8 heads x 32). out: [P][256] bf16.
__global__ __launch_bounds__(256) void attn_k(const u16* __restrict__ qkv, u16* __restrict__ out) {
    const int t = blockIdx.x * 256 + threadIdx.x;
    const int head = t & 7;
    const int p = t >> 3;
    const int b = p >> 12;
    const int ij = p & 4095;
    const int i = ij >> 6, j = ij & 63;
    int r0 = i - 1; r0 = r0 < 0 ? 0 : (r0 > 61 ? 61 : r0);
    int c0 = j - 1; c0 = c0 < 0 ? 0 : (c0 > 61 ? 61 : c0);

    const u16* qp = qkv + (size_t)p * 768 + head * 32;
    float q[32];
#pragma unroll
    for (int ch = 0; ch < 4; ++ch)
        unpack8(*reinterpret_cast<const uint4*>(qp + ch * 8), q + ch * 8);

    const float qscale = 0.17677669529663687f;  // 32^-0.5
    int nbp[9];
    float sc[9];
#pragma unroll
    for (int dr = 0; dr < 3; ++dr)
#pragma unroll
        for (int dc = 0; dc < 3; ++dc) {
            int nb = dr * 3 + dc;
            int np_ = b * 4096 + (r0 + dr) * 64 + (c0 + dc);
            nbp[nb] = np_;
            const u16* kp = qkv + (size_t)np_ * 768 + 256 + head * 32;
            float dot = 0.f;
#pragma unroll
            for (int ch = 0; ch < 4; ++ch) {
                float kf[8];
                unpack8(*reinterpret_cast<const uint4*>(kp + ch * 8), kf);
#pragma unroll
                for (int e = 0; e < 8; ++e) dot += q[ch * 8 + e] * kf[e];
            }
            sc[nb] = dot * qscale;
        }

    float mx = sc[0];
#pragma unroll
    for (int nb = 1; nb < 9; ++nb) mx = fmaxf(mx, sc[nb]);
    float s = 0.f;
#pragma unroll
    for (int nb = 0; nb < 9; ++nb) { sc[nb] = __expf(sc[nb] - mx); s += sc[nb]; }
    float inv = 1.f / s;

    float acc[32];
#pragma unroll
    for (int e = 0; e < 32; ++e) acc[e] = 0.f;
#pragma unroll
    for (int nb = 0; nb < 9; ++nb) {
        const u16* vp = qkv + (size_t)nbp[nb] * 768 + 512 + head * 32;
        float wgt = sc[nb] * inv;
#pragma unroll
        for (int ch = 0; ch < 4; ++ch) {
            float vf[8];
            unpack8(*reinterpret_cast<const uint4*>(vp + ch * 8), vf);
#pragma unroll
            for (int e = 0; e < 8; ++e) acc[ch * 8 + e] += wgt * vf[e];
        }
    }

    u16 ob[32];
#pragma unroll
    for (int e = 0; e < 32; ++e) ob[e] = f2b(acc[e]);
    uint4* ov = reinterpret_cast<uint4*>(ob);
    uint4* og = reinterpret_cast<uint4*>(out + (size_t)p * 256 + head * 32);
#pragma unroll
    for (int ch = 0; ch < 4; ++ch) og[ch] = ov[ch];
}

extern "C" void kernel_launch(void* const* d_in, const int* in_sizes, int n_in,
                              void* d_out, int out_size, void* d_ws, size_t ws_size,
                              hipStream_t stream) {
    const void* h      = d_in[0];
    const void* qkv_w  = d_in[1];
    const void* qkv_b  = d_in[2];
    const void* proj_w = d_in[3];
    const void* proj_b = d_in[4];
    const void* n1_w   = d_in[5];
    const void* n1_b   = d_in[6];
    const void* n2_w   = d_in[7];
    const void* n2_b   = d_in[8];
    const void* w1     = d_in[9];
    const void* b1     = d_in[10];
    const void* w2     = d_in[11];
    const void* b2     = d_in[12];

    char* ws = (char*)d_ws;
    u16* WqkvT  = (u16*)(ws + 0);          // [768][256]
    u16* WprojT = (u16*)(ws + 393216);     // [256][256]
    u16* W1T    = (u16*)(ws + 524288);     // [512][256]
    u16* W2T    = (u16*)(ws + 786432);     // [256][512]
    int* Flag   = (int*)(ws + 1048576);
    char* bufs  = ws + 1049600;

    size_t avail = ws_size > 1049600 ? ws_size - 1049600 : 0;
    int CHUNK = 4096;
    if (avail >= (size_t)65536 * 2048) CHUNK = 65536;
    else if (avail >= (size_t)16384 * 2048) CHUNK = 16384;
    else if (avail >= (size_t)8192 * 2048) CHUNK = 8192;

    u16* H1 = (u16*)bufs;                          // [CHUNK][256] bf16
    u16* S  = (u16*)(bufs + (size_t)CHUNK * 512);  // [CHUNK][768] bf16

    detect_k<<<1, 256, 0, stream>>>(h, Flag);
    transpose_k<<<768, 256, 0, stream>>>(qkv_w, WqkvT, 256, 768, Flag);
    transpose_k<<<256, 256, 0, stream>>>(proj_w, WprojT, 256, 256, Flag);
    transpose_k<<<512, 256, 0, stream>>>(w1, W1T, 256, 512, Flag);
    transpose_k<<<512, 256, 0, stream>>>(w2, W2T, 512, 256, Flag);

    if (CHUNK == 65536) {
        // full-M flow: 6 more launches, hnew kept bf16 inside S region
        u16* HNS = S;                               // [65536][256] bf16 (qkv dead after attn)
        u16* T   = S + (size_t)65536 * 256;         // [65536][512] bf16
        norm_k<<<16384, 256, 0, stream>>>(h, 0, n1_w, n1_b, H1, Flag, 0);
        { dim3 g(6, 512); gemm_bt<0><<<g, 256, 0, stream>>>(H1, WqkvT, qkv_b, nullptr, 0, S, 0, 768, 256, Flag); }
        attn_k<<<2048, 256, 0, stream>>>(S, H1);
        { dim3 g(2, 512); gemm_bt<3><<<g, 256, 0, stream>>>(H1, WprojT, proj_b, h, 0, HNS, 0, 256, 256, Flag); }
        norm_k<<<16384, 256, 0, stream>>>(HNS, 0, n2_w, n2_b, H1, Flag, 1);
        { dim3 g(4, 512); gemm_bt<1><<<g, 256, 0, stream>>>(H1, W1T, b1, nullptr, 0, T, 0, 512, 256, Flag); }
        { dim3 g(2, 512); gemm_bt<4><<<g, 256, 0, stream>>>(T, W2T, b2, HNS, 0, d_out, 0, 256, 512, Flag); }
    } else {
        const int NCH = 65536 / CHUNK;
        for (int c = 0; c < NCH; ++c) {
            size_t off = (size_t)c * CHUNK * 256;
            norm_k<<<CHUNK / 4, 256, 0, stream>>>(h, off, n1_w, n1_b, H1, Flag, 0);
            { dim3 g(6, CHUNK / 128);
              gemm_bt<0><<<g, 256, 0, stream>>>(H1, WqkvT, qkv_b, nullptr, 0, S, 0, 768, 256, Flag); }
            attn_k<<<CHUNK / 32, 256, 0, stream>>>(S, H1);
            { dim3 g(2, CHUNK / 128);
              gemm_bt<2><<<g, 256, 0, stream>>>(H1, WprojT, proj_b, h, off, d_out, off, 256, 256, Flag); }
        }
        for (int c = 0; c < NCH; ++c) {
            size_t off = (size_t)c * CHUNK * 256;
            norm_k<<<CHUNK / 4, 256, 0, stream>>>(d_out, off, n2_w, n2_b, H1, Flag, 0);
            { dim3 g(4, CHUNK / 128);
              gemm_bt<1><<<g, 256, 0, stream>>>(H1, W1T, b1, nullptr, 0, S, 0, 512, 256, Flag); }
            { dim3 g(2, CHUNK / 128);
              gemm_bt<2><<<g, 256, 0, stream>>>(S, W2T, b2, d_out, off, d_out, off, 256, 512, Flag); }
        }
    }
}